// Round 19
// baseline (487.458 us; speedup 1.0000x reference)
//
#include <hip/hip_runtime.h>
#include <hip/hip_bf16.h>

// Problem constants
#define S_TOT 5184      // total sequence
#define S_PAD 5216      // padded V^T row stride (absorbs window-union overreads)
#define T_TXT 64        // text tokens
#define OFF0  64        // start of image0 (32x32)
#define OFF1  1088      // start of image1 (64x64)
#define NHEAD 16
#define CH    64        // channels per head
#define HID   1024
#define BATCH 4
#define BN_TOT (BATCH*NHEAD)   // 64
#define MTOT  (BATCH*S_TOT)    // 20736

typedef __attribute__((ext_vector_type(8))) short bf16x8;
typedef __attribute__((ext_vector_type(8))) _Float16 f16x8;
typedef __attribute__((ext_vector_type(4))) float f32x4;
typedef __attribute__((ext_vector_type(2))) _Float16 h2v;

__device__ __forceinline__ unsigned int f2bf(float x) {
  unsigned int u = __float_as_uint(x);
  unsigned int r = u + 0x7fffu + ((u >> 16) & 1u);
  return r >> 16;
}
__device__ __forceinline__ unsigned short f2h(float x) {
  _Float16 h = (_Float16)x;
  return __builtin_bit_cast(unsigned short, h);
}
__device__ __forceinline__ h2v h2(unsigned int u) { return __builtin_bit_cast(h2v, u); }
__device__ __forceinline__ float fd2(unsigned int a, unsigned int b, float c) {
  return __builtin_amdgcn_fdot2(h2(a), h2(b), c, false);
}
__device__ __forceinline__ unsigned int pklo(unsigned int a, unsigned int b) { return (a & 0xffffu) | (b << 16); }
__device__ __forceinline__ unsigned int pkhi(unsigned int a, unsigned int b) { return (a >> 16) | (b & 0xffff0000u); }
__device__ __forceinline__ f16x8 ld8h(const unsigned short* p) {
  return __builtin_bit_cast(f16x8, *(const uint4*)p);
}

__device__ __forceinline__ void gload_lds16(const short* g, short* l) {
  __builtin_amdgcn_global_load_lds(
      (const __attribute__((address_space(1))) unsigned int*)g,
      (__attribute__((address_space(3))) unsigned int*)l, 16, 0, 0);
}

// ---------------- conversion kernels ----------------
__global__ __launch_bounds__(256) void cvt_bf16(const float* __restrict__ in,
                                                unsigned int* __restrict__ out, int n8) {
  const int i = blockIdx.x * 256 + threadIdx.x;
  if (i >= n8) return;
  const float4 a = ((const float4*)in)[2 * i];
  const float4 b = ((const float4*)in)[2 * i + 1];
  uint4 r;
  r.x = f2bf(a.x) | (f2bf(a.y) << 16);
  r.y = f2bf(a.z) | (f2bf(a.w) << 16);
  r.z = f2bf(b.x) | (f2bf(b.y) << 16);
  r.w = f2bf(b.z) | (f2bf(b.w) << 16);
  ((uint4*)out)[i] = r;
}

__global__ void cvt_T(const float* __restrict__ in, short* __restrict__ out,
                      const int R, const int Cn) {
  __shared__ float t[32][33];
  const int bx = blockIdx.x * 32, by = blockIdx.y * 32;
  const int tx = threadIdx.x, ty = threadIdx.y;
#pragma unroll
  for (int ph = 0; ph < 4; ++ph)
    t[ty + ph * 8][tx] = in[(size_t)(by + ty + ph * 8) * Cn + bx + tx];
  __syncthreads();
#pragma unroll
  for (int ph = 0; ph < 4; ++ph)
    out[(size_t)(bx + ty + ph * 8) * R + by + tx] = (short)f2bf(t[tx][ty + ph * 8]);
}

// f16 transpose: vbuf [bh][s][64] -> vtf [bh*64+ch][S_PAD]
__global__ void cvt_Tv(const unsigned short* __restrict__ in, unsigned short* __restrict__ out) {
  __shared__ unsigned short t[32][33];
  const int bh = blockIdx.z;
  const int c0 = blockIdx.x * 32;
  const int s0 = blockIdx.y * 32;
  const int tx = threadIdx.x, ty = threadIdx.y;
  const unsigned short* src = in + (size_t)bh * S_TOT * CH;
  unsigned short* dst = out + (size_t)bh * CH * S_PAD;
#pragma unroll
  for (int ph = 0; ph < 4; ++ph)
    t[ty + ph * 8][tx] = src[(size_t)(s0 + ty + ph * 8) * CH + c0 + tx];
  __syncthreads();
#pragma unroll
  for (int ph = 0; ph < 4; ++ph)
    dst[(size_t)(c0 + ty + ph * 8) * S_PAD + s0 + tx] = t[tx][ty + ph * 8];
}

// ---------------- 256x256 deep-pipelined bf16 MFMA GEMM ----------------
template<int EPI>
__global__ __launch_bounds__(512) __attribute__((amdgpu_waves_per_eu(2)))
void gemm_mfma256(
    const short* __restrict__ A, const short* __restrict__ BT,
    const float* __restrict__ bias, float* __restrict__ C,
    unsigned short* __restrict__ qbuf, unsigned short* __restrict__ kbuf,
    unsigned short* __restrict__ vbuf,
    const int M, const int N, const int K)
{
  __shared__ short SH[65536];
  const int tid = threadIdx.x;
  const int w = tid >> 6, l = tid & 63;
  const int wm = w >> 2, wn = w & 3;
  const int lr = l & 15, lg = l >> 4;

  int lin;
  {
    const int orig = blockIdx.y * gridDim.x + blockIdx.x;
    const int nwg = gridDim.x * gridDim.y;
    const int q = nwg >> 3, r = nwg & 7;
    const int x = orig & 7, idx = orig >> 3;
    lin = (x < r ? x * (q + 1) : r * (q + 1) + (x - r) * q) + idx;
  }
  const int bm = (lin % gridDim.x) * 256;
  const int bn = (lin / gridDim.x) * 256;

  auto stageA = [&](int tt, int h) {
    const int kb = tt * 64;
    const int lo = ((tt & 1) * 2 + h) * 8192;
#pragma unroll
    for (int c = 0; c < 2; ++c) {
      const int idx = c * 512 + tid;
      const int row = idx >> 3;
      const int col = ((idx & 7) ^ (row & 7)) * 8;
      gload_lds16(A + (size_t)(bm + h * 128 + row) * K + kb + col, SH + lo + idx * 8);
    }
  };
  auto stageB = [&](int tt, int h) {
    const int kb = tt * 64;
    const int lo = 32768 + ((tt & 1) * 2 + h) * 8192;
#pragma unroll
    for (int c = 0; c < 2; ++c) {
      const int idx = c * 512 + tid;
      const int row = idx >> 3;
      const int col = ((idx & 7) ^ (row & 7)) * 8;
      gload_lds16(BT + (size_t)(bn + h * 128 + row) * K + kb + col, SH + lo + idx * 8);
    }
  };

  f32x4 acc[8][4];
#pragma unroll
  for (int m = 0; m < 8; ++m)
#pragma unroll
    for (int n = 0; n < 4; ++n) acc[m][n] = (f32x4){0.f, 0.f, 0.f, 0.f};

  const int NT = K >> 6;
  stageA(0, 0); stageA(0, 1); stageB(0, 0); stageB(0, 1);
  stageA(1, 0); stageA(1, 1); stageB(1, 0); stageB(1, 1);
  asm volatile("s_waitcnt vmcnt(8)" ::: "memory");
  __builtin_amdgcn_s_barrier();
  __builtin_amdgcn_sched_barrier(0);

  const int aoffBase = wm * 8192;
  const int boffBase = 32768 + (wn >> 1) * 8192 + (wn & 1) * 64 * 64;
  const int sw = (lr & 7) << 3;

  for (int t = 0; t < NT; ++t) {
    const int b = t & 1;
    const int ao = b * 16384 + aoffBase;
    const int bo = boffBase + b * 16384;
    bf16x8 af[8], bfr[4];
#pragma unroll
    for (int m = 0; m < 8; ++m)
      af[m] = *(const bf16x8*)&SH[ao + (m * 16 + lr) * 64 + ((lg * 8) ^ sw)];
#pragma unroll
    for (int n = 0; n < 4; ++n)
      bfr[n] = *(const bf16x8*)&SH[bo + (n * 16 + lr) * 64 + ((lg * 8) ^ sw)];
    __builtin_amdgcn_s_setprio(1);
#pragma unroll
    for (int m = 0; m < 8; ++m)
#pragma unroll
      for (int n = 0; n < 4; ++n)
        acc[m][n] = __builtin_amdgcn_mfma_f32_16x16x32_bf16(af[m], bfr[n], acc[m][n], 0, 0, 0);
    __builtin_amdgcn_s_setprio(0);
#pragma unroll
    for (int m = 0; m < 8; ++m)
      af[m] = *(const bf16x8*)&SH[ao + (m * 16 + lr) * 64 + ((32 + lg * 8) ^ sw)];
#pragma unroll
    for (int n = 0; n < 4; ++n)
      bfr[n] = *(const bf16x8*)&SH[bo + (n * 16 + lr) * 64 + ((32 + lg * 8) ^ sw)];
    asm volatile("s_waitcnt lgkmcnt(0)" ::: "memory");
    __builtin_amdgcn_sched_barrier(0);
    __builtin_amdgcn_s_barrier();
    __builtin_amdgcn_sched_barrier(0);
    if (t + 2 < NT) {
      stageA(t + 2, 0); stageA(t + 2, 1); stageB(t + 2, 0); stageB(t + 2, 1);
    }
    __builtin_amdgcn_s_setprio(1);
#pragma unroll
    for (int m = 0; m < 8; ++m)
#pragma unroll
      for (int n = 0; n < 4; ++n)
        acc[m][n] = __builtin_amdgcn_mfma_f32_16x16x32_bf16(af[m], bfr[n], acc[m][n], 0, 0, 0);
    __builtin_amdgcn_s_setprio(0);
    if (t + 2 < NT) asm volatile("s_waitcnt vmcnt(8)" ::: "memory");
    else            asm volatile("s_waitcnt vmcnt(0)" ::: "memory");
    __builtin_amdgcn_s_barrier();
    __builtin_amdgcn_sched_barrier(0);
  }

#pragma unroll
  for (int m = 0; m < 8; ++m) {
    const int row0 = bm + wm * 128 + m * 16 + lg * 4;
#pragma unroll
    for (int n = 0; n < 4; ++n) {
      const int col = bn + wn * 64 + n * 16 + lr;
      const float bv = bias[col];
      if constexpr (EPI == 0) {
#pragma unroll
        for (int i = 0; i < 4; ++i)
          C[(size_t)(row0 + i) * N + col] = acc[m][n][i] + bv;
      } else {
        const int type = col >> 10;
        const int head = (col & 1023) >> 6;
        const int chn  = col & 63;
        unsigned short* dst = (type == 0) ? qbuf : ((type == 1) ? kbuf : vbuf);
        const float sc = (type == 0) ? 0.125f : 1.f;
#pragma unroll
        for (int i = 0; i < 4; ++i) {
          const int row = row0 + i;
          const int b_ = row / S_TOT;
          const int s_ = row - b_ * S_TOT;
          dst[(((size_t)(b_ * NHEAD + head)) * S_TOT + s_) * CH + chn] =
              f2h((acc[m][n][i] + bv) * sc);
        }
      }
    }
  }
}

// ---------------- MFMA img1: 3-phase flash with issue-early V loads (T14) ----------------
__global__ __launch_bounds__(128) __attribute__((amdgpu_waves_per_eu(2, 3)))
void attn_img1_mfma(
    const unsigned short* __restrict__ qb, const unsigned short* __restrict__ kb,
    const unsigned short* __restrict__ vtf, const unsigned short* __restrict__ maskT,
    short* __restrict__ ctx)
{
  __shared__ unsigned short ldsP[2][16][168];
  const int tid = threadIdx.x;
  const int w = tid >> 6, l = tid & 63;
  const int lr = l & 15, lg = l >> 4;
  const int work = (blockIdx.x & 7) * 1024 + (blockIdx.x >> 3);
  const int bh = work >> 7;
  const int qi = (work >> 1) & 63;
  const int qj0 = (work & 1) * 32 + w * 16;
  const int b_ = bh >> 4, head = bh & 15;
  const int s0 = OFF1 + qi * 64 + qj0;
  const size_t vrowbase = (size_t)bh * CH;
  unsigned short* myP = &ldsP[w][0][0];

  const unsigned short* qrow = qb + ((size_t)bh * S_TOT + s0 + lr) * CH + lg * 8;
  const f16x8 aq0 = ld8h(qrow);
  const f16x8 aq1 = ld8h(qrow + 32);

  float m[4], lsum[4];
  f32x4 acc[4];
#pragma unroll
  for (int i = 0; i < 4; ++i) { m[i] = -1e30f; lsum[i] = 0.f; }
#pragma unroll
  for (int n = 0; n < 4; ++n) acc[n] = (f32x4){0.f, 0.f, 0.f, 0.f};

  // ======== Phase C: text keys (masked) ========
  {
    f32x4 sC[4];
    const unsigned short* kb0 = kb + ((size_t)bh * S_TOT) * CH + lg * 8;
#pragma unroll
    for (int kt = 0; kt < 4; ++kt) {
      const unsigned short* krow = kb0 + (kt * 16 + lr) * CH;
      f32x4 a = (f32x4){0.f, 0.f, 0.f, 0.f};
      a = __builtin_amdgcn_mfma_f32_16x16x32_f16(aq0, ld8h(krow), a, 0, 0, 0);
      a = __builtin_amdgcn_mfma_f32_16x16x32_f16(aq1, ld8h(krow + 32), a, 0, 0, 0);
      sC[kt] = a;
    }
    // T14: issue V^T loads now (addresses independent of P); latency hides under softmax
    uint4 vC[8];
#pragma unroll
    for (int kt = 0; kt < 2; ++kt)
#pragma unroll
      for (int n = 0; n < 4; ++n)
        vC[kt * 4 + n] = *(const uint4*)(vtf + (vrowbase + n * 16 + lr) * S_PAD + kt * 32 + lg * 8);
#pragma unroll
    for (int kt = 0; kt < 4; ++kt) {
      const unsigned short* mrow = maskT + (size_t)(kt * 16 + lr) * MTOT + (size_t)b_ * S_TOT + s0 + lg * 4;
#pragma unroll
      for (int i = 0; i < 4; ++i) {
        const float mv = __uint_as_float(((unsigned int)mrow[i]) << 16);
        sC[kt][i] = sC[kt][i] * mv - 10000.f * (1.f - mv);
      }
    }
    float rsc[4], la[4];
#pragma unroll
    for (int i = 0; i < 4; ++i) {
      float mx = fmaxf(fmaxf(sC[0][i], sC[1][i]), fmaxf(sC[2][i], sC[3][i]));
      mx = fmaxf(mx, __shfl_xor(mx, 1));
      mx = fmaxf(mx, __shfl_xor(mx, 2));
      mx = fmaxf(mx, __shfl_xor(mx, 4));
      mx = fmaxf(mx, __shfl_xor(mx, 8));
      const float mn = fmaxf(m[i], mx);
      rsc[i] = __expf(m[i] - mn);
      m[i] = mn;
      la[i] = 0.f;
    }
#pragma unroll
    for (int kt = 0; kt < 4; ++kt)
#pragma unroll
      for (int i = 0; i < 4; ++i) {
        const float p = __expf(sC[kt][i] - m[i]);
        la[i] += p;
        myP[(lg * 4 + i) * 168 + kt * 16 + lr] = f2h(p);
      }
#pragma unroll
    for (int i = 0; i < 4; ++i) {
      float li = la[i];
      li += __shfl_xor(li, 1);
      li += __shfl_xor(li, 2);
      li += __shfl_xor(li, 4);
      li += __shfl_xor(li, 8);
      lsum[i] = lsum[i] * rsc[i] + li;
#pragma unroll
      for (int n = 0; n < 4; ++n) acc[n][i] *= rsc[i];
    }
#pragma unroll
    for (int kt = 0; kt < 2; ++kt) {
      const f16x8 ap = __builtin_bit_cast(f16x8, *(const uint4*)&myP[lr * 168 + kt * 32 + lg * 8]);
#pragma unroll
      for (int n = 0; n < 4; ++n)
        acc[n] = __builtin_amdgcn_mfma_f32_16x16x32_f16(ap, __builtin_bit_cast(f16x8, vC[kt * 4 + n]), acc[n], 0, 0, 0);
    }
  }

  // ======== Phase A: 7x7 full window over k0 (32x32) ========
  {
    const int ki0 = qi >> 1, cb = (qj0 >> 1) - 3;
    f32x4 sA[7];
#pragma unroll
    for (int rr = 0; rr < 7; ++rr) sA[rr] = (f32x4){-1e30f, -1e30f, -1e30f, -1e30f};
    const unsigned short* kbA = kb + ((size_t)bh * S_TOT + OFF0) * CH + lg * 8;
    const int kjc = min(max(cb + lr, 0), 31);
#pragma unroll
    for (int rr = 0; rr < 7; ++rr) {
      const int ki = ki0 + rr - 3;
      if ((unsigned)ki < 32u) {
        const unsigned short* krow = kbA + (ki * 32 + kjc) * CH;
        f32x4 a = (f32x4){0.f, 0.f, 0.f, 0.f};
        a = __builtin_amdgcn_mfma_f32_16x16x32_f16(aq0, ld8h(krow), a, 0, 0, 0);
        a = __builtin_amdgcn_mfma_f32_16x16x32_f16(aq1, ld8h(krow + 32), a, 0, 0, 0);
        sA[rr] = a;
      }
    }
    // T14: issue V^T loads for phase A now
    uint4 vA[16];
#pragma unroll
    for (int kt = 0; kt < 4; ++kt) {
      const int rowidx = 2 * kt + (lg >> 1);
      const int kiv = min(max(ki0 + rowidx - 3, 0), 31);
      const int sbase = OFF0 + kiv * 32 + cb + (lg & 1) * 8;
#pragma unroll
      for (int n = 0; n < 4; ++n)
        vA[kt * 4 + n] = *(const uint4*)(vtf + (vrowbase + n * 16 + lr) * S_PAD + sbase);
    }
    const int kjA = cb + lr;
    float pmax[4] = {-1e30f, -1e30f, -1e30f, -1e30f};
#pragma unroll
    for (int rr = 0; rr < 7; ++rr) {
      const int ki = ki0 + rr - 3;
      const bool rv = (unsigned)ki < 32u;
#pragma unroll
      for (int i = 0; i < 4; ++i) {
        const int kjq = (qj0 + lg * 4 + i) >> 1;
        const int dj = kjA - kjq;
        const bool ok = rv && dj >= -3 && dj <= 3 && kjA >= 0 && kjA < 32;
        sA[rr][i] = ok ? sA[rr][i] : -1e30f;
        pmax[i] = fmaxf(pmax[i], sA[rr][i]);
      }
    }
    float rsc[4], la[4];
#pragma unroll
    for (int i = 0; i < 4; ++i) {
      float mx = pmax[i];
      mx = fmaxf(mx, __shfl_xor(mx, 1));
      mx = fmaxf(mx, __shfl_xor(mx, 2));
      mx = fmaxf(mx, __shfl_xor(mx, 4));
      mx = fmaxf(mx, __shfl_xor(mx, 8));
      const float mn = fmaxf(m[i], mx);
      rsc[i] = __expf(m[i] - mn);
      m[i] = mn;
      la[i] = 0.f;
    }
#pragma unroll
    for (int rr = 0; rr < 7; ++rr)
#pragma unroll
      for (int i = 0; i < 4; ++i) {
        const float p = __expf(sA[rr][i] - m[i]);
        la[i] += p;
        myP[(lg * 4 + i) * 168 + rr * 16 + lr] = f2h(p);
      }
#pragma unroll
    for (int j2 = 0; j2 < 4; ++j2)
      myP[lr * 168 + 112 + lg * 4 + j2] = 0;
#pragma unroll
    for (int i = 0; i < 4; ++i) {
      float li = la[i];
      li += __shfl_xor(li, 1);
      li += __shfl_xor(li, 2);
      li += __shfl_xor(li, 4);
      li += __shfl_xor(li, 8);
      lsum[i] = lsum[i] * rsc[i] + li;
#pragma unroll
      for (int n = 0; n < 4; ++n) acc[n][i] *= rsc[i];
    }
#pragma unroll
    for (int kt = 0; kt < 4; ++kt) {
      const f16x8 ap = __builtin_bit_cast(f16x8, *(const uint4*)&myP[lr * 168 + kt * 32 + lg * 8]);
#pragma unroll
      for (int n = 0; n < 4; ++n)
        acc[n] = __builtin_amdgcn_mfma_f32_16x16x32_f16(ap, __builtin_bit_cast(f16x8, vA[kt * 4 + n]), acc[n], 0, 0, 0);
    }
  }

  // ======== Phase B: 9x9 causal window over k1 (64x64) ========
  {
    const int cbB = qj0 - 4;
    f32x4 sB[10];
#pragma unroll
    for (int rr = 0; rr < 10; ++rr) sB[rr] = (f32x4){-1e30f, -1e30f, -1e30f, -1e30f};
    const unsigned short* kbB = kb + ((size_t)bh * S_TOT + OFF1) * CH + lg * 8;
#pragma unroll
    for (int rr = 0; rr < 5; ++rr) {
      const int ki = qi + rr - 4;
      if (ki >= 0) {
#pragma unroll
        for (int t = 0; t < 2; ++t) {
          const int kjc = min(max(cbB + t * 16 + lr, 0), 63);
          const unsigned short* krow = kbB + (ki * 64 + kjc) * CH;
          f32x4 a = (f32x4){0.f, 0.f, 0.f, 0.f};
          a = __builtin_amdgcn_mfma_f32_16x16x32_f16(aq0, ld8h(krow), a, 0, 0, 0);
          a = __builtin_amdgcn_mfma_f32_16x16x32_f16(aq1, ld8h(krow + 32), a, 0, 0, 0);
          sB[rr * 2 + t] = a;
        }
      }
    }
    // T14: issue V^T loads for phase B now
    uint4 vB[20];
#pragma unroll
    for (int kt = 0; kt < 5; ++kt) {
      const int kiv = max(qi + kt - 4, 0);
      const int sbase = OFF1 + kiv * 64 + cbB + lg * 8;
#pragma unroll
      for (int n = 0; n < 4; ++n)
        vB[kt * 4 + n] = *(const uint4*)(vtf + (vrowbase + n * 16 + lr) * S_PAD + sbase);
    }
    float pmax[4] = {-1e30f, -1e30f, -1e30f, -1e30f};
#pragma unroll
    for (int rr = 0; rr < 5; ++rr) {
      const int djmax = (rr == 4) ? 0 : 4;
#pragma unroll
      for (int t = 0; t < 2; ++t) {
        const int kj = cbB + t * 16 + lr;
#pragma unroll
        for (int i = 0; i < 4; ++i) {
          const int qj = qj0 + lg * 4 + i;
          const int dj = kj - qj;
          const bool ok = dj >= -4 && dj <= djmax && kj >= 0 && kj < 64;
          sB[rr * 2 + t][i] = ok ? sB[rr * 2 + t][i] : -1e30f;
          pmax[i] = fmaxf(pmax[i], sB[rr * 2 + t][i]);
        }
      }
    }
    float rsc[4], la[4];
#pragma unroll
    for (int i = 0; i < 4; ++i) {
      float mx = pmax[i];
      mx = fmaxf(mx, __shfl_xor(mx, 1));
      mx = fmaxf(mx, __shfl_xor(mx, 2));
      mx = fmaxf(mx, __shfl_xor(mx, 4));
      mx = fmaxf(mx, __shfl_xor(mx, 8));
      const float mn = fmaxf(m[i], mx);
      rsc[i] = __expf(m[i] - mn);
      m[i] = mn;
      la[i] = 0.f;
    }
#pragma unroll
    for (int rr = 0; rr < 5; ++rr)
#pragma unroll
      for (int t = 0; t < 2; ++t)
#pragma unroll
        for (int i = 0; i < 4; ++i) {
          const float p = __expf(sB[rr * 2 + t][i] - m[i]);
          la[i] += p;
          myP[(lg * 4 + i) * 168 + rr * 32 + t * 16 + lr] = f2h(p);
        }
#pragma unroll
    for (int i = 0; i < 4; ++i) {
      float li = la[i];
      li += __shfl_xor(li, 1);
      li += __shfl_xor(li, 2);
      li += __shfl_xor(li, 4);
      li += __shfl_xor(li, 8);
      lsum[i] = lsum[i] * rsc[i] + li;
#pragma unroll
      for (int n = 0; n < 4; ++n) acc[n][i] *= rsc[i];
    }
#pragma unroll
    for (int kt = 0; kt < 5; ++kt) {
      const f16x8 ap = __builtin_bit_cast(f16x8, *(const uint4*)&myP[lr * 168 + kt * 32 + lg * 8]);
#pragma unroll
      for (int n = 0; n < 4; ++n)
        acc[n] = __builtin_amdgcn_mfma_f32_16x16x32_f16(ap, __builtin_bit_cast(f16x8, vB[kt * 4 + n]), acc[n], 0, 0, 0);
    }
  }

  // ======== finalize ========
  const int ki0f = qi >> 1;
#pragma unroll
  for (int i = 0; i < 4; ++i) {
    const int qj = qj0 + lg * 4 + i;
    const int kjq = qj >> 1;
    const int nInvA = max(0, 3 - ki0f) + max(0, ki0f - 28);
    const int oobA  = max(0, 3 - kjq) + max(0, kjq - 28);
    const int nInvB = max(0, 4 - qi);
    const int oobB  = max(0, 4 - qj) + max(0, qj - 59);
    const int cnt = nInvA * 7 + (7 - nInvA) * oobA
                  + nInvB * 9 + (4 - nInvB) * oobB + max(0, 4 - qj);
    const float lf = lsum[i] + (float)cnt * __expf(-m[i]);
    const float inv = 1.f / lf;
    short* cp = ctx + ((size_t)(b_ * S_TOT) + s0 + lg * 4 + i) * HID + head * CH;
#pragma unroll
    for (int n = 0; n < 4; ++n)
      cp[n * 16 + lr] = (short)f2bf(acc[n][i] * inv);
  }
}

// ---------------- MFMA img0: text + 9x9 causal(k0), single-softmax flash ----------------
__global__ __launch_bounds__(128) __attribute__((amdgpu_waves_per_eu(2, 8)))
void attn_img0_mfma(
    const unsigned short* __restrict__ qb, const unsigned short* __restrict__ kb,
    const unsigned short* __restrict__ vtf, const unsigned short* __restrict__ maskT,
    short* __restrict__ ctx)
{
  __shared__ unsigned short ldsP[2][16][168];
  const int tid = threadIdx.x;
  const int w = tid >> 6, l = tid & 63;
  const int lr = l & 15, lg = l >> 4;
  const int swz = (blockIdx.x & 7) * ((BN_TOT * 32) >> 3) + (blockIdx.x >> 3);
  const int bh = swz >> 5;
  const int qi = swz & 31;
  const int qj0 = w * 16;
  const int b_ = bh >> 4, head = bh & 15;
  const int s0 = OFF0 + qi * 32 + qj0;
  const size_t vrowbase = (size_t)bh * CH;
  unsigned short* myP = &ldsP[w][0][0];

  const unsigned short* qrow = qb + ((size_t)bh * S_TOT + s0 + lr) * CH + lg * 8;
  const f16x8 aq0 = ld8h(qrow);
  const f16x8 aq1 = ld8h(qrow + 32);

  f32x4 sC[4];
  {
    const unsigned short* kb0 = kb + ((size_t)bh * S_TOT) * CH + lg * 8;
#pragma unroll
    for (int kt = 0; kt < 4; ++kt) {
      const unsigned short* krow = kb0 + (kt * 16 + lr) * CH;
      f32x4 a = (f32x4){0.f, 0.f, 0.f, 0.f};
      a = __builtin_amdgcn_mfma_f32_16x16x32_f16(aq0, ld8h(krow), a, 0, 0, 0);
      a = __builtin_amdgcn_mfma_f32_16x16x32_f16(aq1, ld8h(krow + 32), a, 0, 0, 0);
      sC[kt] = a;
    }
  }
  const int cbB = qj0 - 4;
  f32x4 sB[10];
  {
#pragma unroll
    for (int rr = 0; rr < 10; ++rr) sB[rr] = (f32x4){-1e30f, -1e30f, -1e30f, -1e30f};
    const unsigned short* kbB = kb + ((size_t)bh * S_TOT + OFF0) * CH + lg * 8;
#pragma unroll
    for (int rr = 0; rr < 5; ++rr) {
      const int ki = qi + rr - 4;
      if (ki >= 0) {
#pragma unroll
        for (int t = 0; t < 2; ++t) {
          const int kjc = min(max(cbB + t * 16 + lr, 0), 31);
          const unsigned short* krow = kbB + (ki * 32 + kjc) * CH;
          f32x4 a = (f32x4){0.f, 0.f, 0.f, 0.f};
          a = __builtin_amdgcn_mfma_f32_16x16x32_f16(aq0, ld8h(krow), a, 0, 0, 0);
          a = __builtin_amdgcn_mfma_f32_16x16x32_f16(aq1, ld8h(krow + 32), a, 0, 0, 0);
          sB[rr * 2 + t] = a;
        }
      }
    }
  }

#pragma unroll
  for (int kt = 0; kt < 4; ++kt) {
    const unsigned short* mrow = maskT + (size_t)(kt * 16 + lr) * MTOT + (size_t)b_ * S_TOT + s0 + lg * 4;
#pragma unroll
    for (int i = 0; i < 4; ++i) {
      const float mv = __uint_as_float(((unsigned int)mrow[i]) << 16);
      sC[kt][i] = sC[kt][i] * mv - 10000.f * (1.f - mv);
    }
  }
#pragma unroll
  for (int rr = 0; rr < 5; ++rr) {
    const int djmax = (rr == 4) ? 0 : 4;
#pragma unroll
    for (int t = 0; t < 2; ++t) {
      const int kj = cbB + t * 16 + lr;
#pragma unroll
      for (int i = 0; i < 4; ++i) {
        const int qj = qj0 + lg * 4 + i;
        const int dj = kj - qj;
        const bool ok = dj >= -4 && dj <= djmax && kj >= 0 && kj < 32;
        sB[rr * 2 + t][i] = ok ? sB[rr * 2 + t][i] : -1e30f;
      }
    }
  }

  float m[4], lsum[4];
#pragma unroll
  for (int i = 0; i < 4; ++i) {
    float mx = fmaxf(fmaxf(sC[0][i], sC[1][i]), fmaxf(sC[2][i], sC[3][i]));
#pragma unroll
    for (int rr = 0; rr < 10; ++rr) mx = fmaxf(mx, sB[rr][i]);
    mx = fmaxf(mx, __shfl_xor(mx, 1));
    mx = fmaxf(mx, __shfl_xor(mx, 2));
    mx = fmaxf(mx, __shfl_xor(mx, 4));
    mx = fmaxf(mx, __shfl_xor(mx, 8));
    m[i] = mx;
    float li = 0.f;
#pragma unroll
    for (int kt = 0; kt < 4; ++kt) { const float p = __expf(sC[kt][i] - mx); sC[kt][i] = p; li += p; }
#pragma unroll
    for (int rr = 0; rr < 10; ++rr) { const float p = __expf(sB[rr][i] - mx); sB[rr][i] = p; li += p; }
    li += __shfl_xor(li, 1);
    li += __shfl_xor(li, 2);
    li += __shfl_xor(li, 4);
    li += __shfl_xor(li, 8);
    lsum[i] = li;
  }

  f32x4 acc[4];
#pragma unroll
  for (int n = 0; n < 4; ++n) acc[n] = (f32x4){0.f, 0.f, 0.f, 0.f};

  {
#pragma unroll
    for (int kt = 0; kt < 4; ++kt)
#pragma unroll
      for (int i = 0; i < 4; ++i)
        myP[(lg * 4 + i) * 168 + kt * 16 + lr] = f2h(sC[kt][i]);
#pragma unroll
    for (int kt = 0; kt < 2; ++kt) {
      const f16x8 ap = __builtin_bit_cast(f16x8, *(const uint4*)&myP[lr * 168 + kt * 32 + lg * 8]);
      const int sbase = kt * 32 + lg * 8;
#pragma unroll
      for (int n = 0; n < 4; ++n) {
        const f16x8 bv = ld8h(vtf + (vrowbase + n * 16 + lr) * S_PAD + sbase);
        acc[n] = __builtin_amdgcn_mfma_f32_16x16x32_f16(ap, bv, acc[n], 0, 0, 0);
      }
    }
  }
  {
#pragma unroll
    for (int rr = 0; rr < 5; ++rr)
#pragma unroll
      for (int t = 0; t < 2; ++t)
#pragma unroll
        for (int i = 0; i < 4; ++i)
          myP[(lg * 4 + i) * 168 + rr * 32 + t * 16 + lr] = f2h(sB[rr * 2 + t][i]);
#pragma unroll
    for (int kt = 0; kt < 5; ++kt) {
      const f16x8 ap = __builtin_bit_cast(f16x8, *(const uint4*)&myP[lr * 168 + kt * 32 + lg * 8]);
      const int kiv = max(qi + kt - 4, 0);
      const int sbase = OFF0 + kiv * 32 + cbB + lg * 8;
#pragma unroll
      for (int n = 0; n < 4; ++n) {
        const f16x8 bv = ld8h(vtf + (vrowbase + n * 16 + lr) * S_PAD + sbase);
        acc[n] = __builtin_amdgcn_mfma_f32_16x16x32_f16(ap, bv, acc[n], 0, 0, 0);
      }
    }
  }

#pragma unroll
  for (int i = 0; i < 4; ++i) {
    const int qj = qj0 + lg * 4 + i;
    const int nInvB = max(0, 4 - qi);
    const int oobB  = max(0, 4 - qj) + max(0, qj - 27);
    const int cnt = nInvB * 9 + (4 - nInvB) * oobB + max(0, 4 - qj);
    const float lf = lsum[i] + (float)cnt * __expf(-m[i]);
    const float inv = 1.f / lf;
    short* cp = ctx + ((size_t)(b_ * S_TOT) + s0 + lg * 4 + i) * HID + head * CH;
#pragma unroll
    for (int n = 0; n < 4; ++n)
      cp[n * 16 + lr] = (short)f2bf(acc[n][i] * inv);
  }
}

// ---------------- scalar attention core (f16, dot2, 8 lanes/query) ----------------
__device__ __forceinline__ float dot8h(const uint4 qd, const unsigned short* __restrict__ kp) {
  const uint4 a = *(const uint4*)kp;
  float s = 0.f;
  s = fd2(a.x, qd.x, s); s = fd2(a.y, qd.y, s);
  s = fd2(a.z, qd.z, s); s = fd2(a.w, qd.w, s);
  return s;
}
__device__ __forceinline__ void pv2d(float& a0, float& a1, unsigned int dA, unsigned int dB, h2v pp) {
  a0 = __builtin_amdgcn_fdot2(h2(pklo(dA, dB)), pp, a0, false);
  a1 = __builtin_amdgcn_fdot2(h2(pkhi(dA, dB)), pp, a1, false);
}
__device__ __forceinline__ void pv2q(float* __restrict__ acc, uint4 A, uint4 B, h2v pp) {
  pv2d(acc[0], acc[1], A.x, B.x, pp);
  pv2d(acc[2], acc[3], A.y, B.y, pp);
  pv2d(acc[4], acc[5], A.z, B.z, pp);
  pv2d(acc[6], acc[7], A.w, B.w, pp);
}

template<int W, bool MASKED>
__device__ __forceinline__ void row_upd(const uint4 qd,
                                        const unsigned short* __restrict__ krow,
                                        const unsigned short* __restrict__ vrow,
                                        const int kj0, const int limit,
                                        const unsigned short* __restrict__ maskT,
                                        const int rowIdx,
                                        float& m, float& l, float* __restrict__ acc, int& cnt) {
  float s[W];
#pragma unroll
  for (int j = 0; j < W; ++j) {
    const int kj = kj0 + j;
    const bool ok = (unsigned)kj < (unsigned)limit;
    float d = dot8h(qd, krow + (ok ? kj : 0) * CH);
    d += __shfl_xor(d, 1);
    d += __shfl_xor(d, 2);
    d += __shfl_xor(d, 4);
    if constexpr (MASKED) {
      const float mv = __uint_as_float(((unsigned int)maskT[(size_t)kj * MTOT + rowIdx]) << 16);
      s[j] = d * mv - 10000.f * (1.f - mv);
    } else {
      s[j] = ok ? d : -1e30f;
      cnt += ok ? 0 : 1;
    }
  }
  float smax = s[0];
#pragma unroll
  for (int j = 1; j < W; ++j) smax = fmaxf(smax, s[j]);
  const float mn = fmaxf(m, smax);
  const float r = __expf(m - mn);
  m = mn;
  l *= r;
#pragma unroll
  for (int i = 0; i < 8; ++i) acc[i] *= r;
  float p[W];
#pragma unroll
  for (int j = 0; j < W; ++j) { p[j] = __expf(s[j] - mn); l += p[j]; }
#pragma unroll
  for (int j = 0; j < W; j += 2) {
    const int kja = kj0 + j;
    const bool oka = (unsigned)kja < (unsigned)limit;
    const uint4 A = *(const uint4*)(vrow + (oka ? kja : 0) * CH);
    uint4 B; float pb;
    if (j + 1 < W) {
      const int kjb = kja + 1;
      const bool okb = (unsigned)kjb < (unsigned)limit;
      B = *(const uint4*)(vrow + (okb ? kjb : 0) * CH);
      pb = p[j + 1];
    } else {
      B = A; pb = 0.f;
    }
    const h2v pp = __builtin_bit_cast(h2v, __builtin_amdgcn_cvt_pkrtz(p[j], pb));
    pv2q(acc, A, B, pp);
  }
}

__device__ __forceinline__ void store_q8(short* ctx, size_t base,
                                         const float* acc, float inv) {
  unsigned int* cp = (unsigned int*)(ctx + base);
#pragma unroll
  for (int i = 0; i < 4; ++i)
    cp[i] = f2bf(acc[2 * i] * inv) | (f2bf(acc[2 * i + 1] * inv) << 16);
}

// ---------------- attention: text queries (scalar) ----------------
__global__ __launch_bounds__(256) __attribute__((amdgpu_waves_per_eu(4, 8)))
void attn_text(
    const unsigned short* __restrict__ qb, const unsigned short* __restrict__ kb,
    const unsigned short* __restrict__ vb, const unsigned short* __restrict__ maskT,
    short* __restrict__ ctx)
{
  const int t = blockIdx.x * 256 + threadIdx.x;
  const int oct = t & 7;
  const int qidx = t >> 3;
  const int bh = qidx >> 6;
  const int tq = qidx & 63;
  const int b_ = bh >> 4, head = bh & 15;

  const uint4 qd = *(const uint4*)(qb + ((size_t)bh * S_TOT + tq) * CH + oct * 8);

  float m = -1e30f, l = 0.f;
  float acc[8];
#pragma unroll
  for (int i = 0; i < 8; ++i) acc[i] = 0.f;
  int cnt = 0;

  const unsigned short* kt = kb + (size_t)bh * S_TOT * CH + oct * 8;
  const unsigned short* vt = vb + (size_t)bh * S_TOT * CH + oct * 8;
  const int rowIdx = b_ * S_TOT + tq;
  for (int t8 = 0; t8 < 8; ++t8)
    row_upd<8, true>(qd, kt, vt, t8 * 8, T_TXT, maskT, rowIdx, m, l, acc, cnt);
  store_q8(ctx, ((size_t)rowIdx) * HID + head * CH + oct * 8, acc, 1.f / l);
}

// ---------------- launch ----------------
extern "C" void kernel_launch(void* const* d_in, const int* in_sizes, int n_in,
                              void* d_out, int out_size, void* d_ws, size_t ws_size,
                              hipStream_t stream) {
  const float* hidden = (const float*)d_in[0];
  const float* mask   = (const float*)d_in[1];
  const float* w_qkv  = (const float*)d_in[2];
  const float* b_qkv  = (const float*)d_in[3];
  const float* w_out  = (const float*)d_in[4];
  const float* b_out  = (const float*)d_in[5];
  float* out = (float*)d_out;

  const size_t NB = (size_t)BN_TOT * S_TOT * CH;
  unsigned short* qbuf = (unsigned short*)d_ws;    // f16
  unsigned short* kbuf = qbuf + NB;
  unsigned short* vbuf = kbuf + NB;
  short* hbf   = (short*)(vbuf + NB);              // hidden bf16; later ALIASED as ctx bf16
  short* wqkvT = hbf + NB;
  short* woutT = wqkvT + (size_t)3072 * 1024;
  short* maskT = woutT + (size_t)1024 * 1024;
  unsigned short* vtf = (unsigned short*)(maskT + (size_t)T_TXT * MTOT);  // V^T [64*64][S_PAD]

  // 0) conversions
  cvt_bf16<<<(int)((NB / 8 + 255) / 256), 256, 0, stream>>>(hidden, (unsigned int*)hbf, (int)(NB / 8));
  cvt_T<<<dim3(3072 / 32, 1024 / 32), dim3(32, 8), 0, stream>>>(w_qkv, wqkvT, 1024, 3072);
  cvt_T<<<dim3(1024 / 32, 1024 / 32), dim3(32, 8), 0, stream>>>(w_out, woutT, 1024, 1024);
  cvt_T<<<dim3(T_TXT / 32, MTOT / 32), dim3(32, 8), 0, stream>>>(mask, maskT, MTOT, T_TXT);

  // 1) QKV projection (256x256 deep-pipelined) with f16 q/k/v scatter epilogue
  gemm_mfma256<1><<<dim3(MTOT / 256, 3072 / 256), 512, 0, stream>>>(
      hbf, wqkvT, b_qkv, nullptr, qbuf, kbuf, vbuf, MTOT, 3072, 1024);

  // 1b) coalesced V transpose: vbuf -> vtf
  cvt_Tv<<<dim3(CH / 32, S_TOT / 32, BN_TOT), dim3(32, 8), 0, stream>>>(vbuf, vtf);

  // 2) attention (all-MFMA for image queries; XCD-chunked swizzle)
  short* ctx = hbf;
  attn_text<<<(BN_TOT * T_TXT * 8) / 256, 256, 0, stream>>>(qbuf, kbuf, vbuf, (unsigned short*)maskT, ctx);
  attn_img0_mfma<<<BN_TOT * 32, 128, 0, stream>>>(qbuf, kbuf, vtf, (unsigned short*)maskT, ctx);
  attn_img1_mfma<<<BN_TOT * 64 * 2, 128, 0, stream>>>(qbuf, kbuf, vtf, (unsigned short*)maskT, ctx);

  // 3) output projection (256x256 deep-pipelined)
  gemm_mfma256<0><<<dim3(MTOT / 256, 1024 / 256), 512, 0, stream>>>(
      ctx, woutT, b_out, out, nullptr, nullptr, nullptr, MTOT, 1024, 1024);
}

// Round 20
// 483.563 us; speedup vs baseline: 1.0081x; 1.0081x over previous
//
#include <hip/hip_runtime.h>
#include <hip/hip_bf16.h>

// Problem constants
#define S_TOT 5184      // total sequence
#define S_PAD 5216      // padded V^T row stride (absorbs window-union overreads)
#define T_TXT 64        // text tokens
#define OFF0  64        // start of image0 (32x32)
#define OFF1  1088      // start of image1 (64x64)
#define NHEAD 16
#define CH    64        // channels per head
#define HID   1024
#define BATCH 4
#define BN_TOT (BATCH*NHEAD)   // 64
#define MTOT  (BATCH*S_TOT)    // 20736

typedef __attribute__((ext_vector_type(8))) short bf16x8;
typedef __attribute__((ext_vector_type(8))) _Float16 f16x8;
typedef __attribute__((ext_vector_type(4))) float f32x4;
typedef __attribute__((ext_vector_type(2))) _Float16 h2v;

__device__ __forceinline__ unsigned int f2bf(float x) {
  unsigned int u = __float_as_uint(x);
  unsigned int r = u + 0x7fffu + ((u >> 16) & 1u);
  return r >> 16;
}
__device__ __forceinline__ unsigned short f2h(float x) {
  _Float16 h = (_Float16)x;
  return __builtin_bit_cast(unsigned short, h);
}
__device__ __forceinline__ h2v h2(unsigned int u) { return __builtin_bit_cast(h2v, u); }
__device__ __forceinline__ float fd2(unsigned int a, unsigned int b, float c) {
  return __builtin_amdgcn_fdot2(h2(a), h2(b), c, false);
}
__device__ __forceinline__ unsigned int pklo(unsigned int a, unsigned int b) { return (a & 0xffffu) | (b << 16); }
__device__ __forceinline__ unsigned int pkhi(unsigned int a, unsigned int b) { return (a >> 16) | (b & 0xffff0000u); }
__device__ __forceinline__ f16x8 ld8h(const unsigned short* p) {
  return __builtin_bit_cast(f16x8, *(const uint4*)p);
}

__device__ __forceinline__ void gload_lds16(const short* g, short* l) {
  __builtin_amdgcn_global_load_lds(
      (const __attribute__((address_space(1))) unsigned int*)g,
      (__attribute__((address_space(3))) unsigned int*)l, 16, 0, 0);
}

// ---------------- conversion kernels ----------------
__global__ __launch_bounds__(256) void cvt_bf16(const float* __restrict__ in,
                                                unsigned int* __restrict__ out, int n8) {
  const int i = blockIdx.x * 256 + threadIdx.x;
  if (i >= n8) return;
  const float4 a = ((const float4*)in)[2 * i];
  const float4 b = ((const float4*)in)[2 * i + 1];
  uint4 r;
  r.x = f2bf(a.x) | (f2bf(a.y) << 16);
  r.y = f2bf(a.z) | (f2bf(a.w) << 16);
  r.z = f2bf(b.x) | (f2bf(b.y) << 16);
  r.w = f2bf(b.z) | (f2bf(b.w) << 16);
  ((uint4*)out)[i] = r;
}

__global__ void cvt_T(const float* __restrict__ in, short* __restrict__ out,
                      const int R, const int Cn) {
  __shared__ float t[32][33];
  const int bx = blockIdx.x * 32, by = blockIdx.y * 32;
  const int tx = threadIdx.x, ty = threadIdx.y;
#pragma unroll
  for (int ph = 0; ph < 4; ++ph)
    t[ty + ph * 8][tx] = in[(size_t)(by + ty + ph * 8) * Cn + bx + tx];
  __syncthreads();
#pragma unroll
  for (int ph = 0; ph < 4; ++ph)
    out[(size_t)(bx + ty + ph * 8) * R + by + tx] = (short)f2bf(t[tx][ty + ph * 8]);
}

// f16 transpose: vbuf [bh][s][64] -> vtf [bh*64+ch][S_PAD]
__global__ void cvt_Tv(const unsigned short* __restrict__ in, unsigned short* __restrict__ out) {
  __shared__ unsigned short t[32][33];
  const int bh = blockIdx.z;
  const int c0 = blockIdx.x * 32;
  const int s0 = blockIdx.y * 32;
  const int tx = threadIdx.x, ty = threadIdx.y;
  const unsigned short* src = in + (size_t)bh * S_TOT * CH;
  unsigned short* dst = out + (size_t)bh * CH * S_PAD;
#pragma unroll
  for (int ph = 0; ph < 4; ++ph)
    t[ty + ph * 8][tx] = src[(size_t)(s0 + ty + ph * 8) * CH + c0 + tx];
  __syncthreads();
#pragma unroll
  for (int ph = 0; ph < 4; ++ph)
    dst[(size_t)(c0 + ty + ph * 8) * S_PAD + s0 + tx] = t[tx][ty + ph * 8];
}

// ---------------- 256x256 deep-pipelined bf16 MFMA GEMM ----------------
template<int EPI>
__global__ __launch_bounds__(512) __attribute__((amdgpu_waves_per_eu(2)))
void gemm_mfma256(
    const short* __restrict__ A, const short* __restrict__ BT,
    const float* __restrict__ bias, float* __restrict__ C,
    unsigned short* __restrict__ qbuf, unsigned short* __restrict__ kbuf,
    unsigned short* __restrict__ vbuf,
    const int M, const int N, const int K)
{
  __shared__ short SH[65536];
  const int tid = threadIdx.x;
  const int w = tid >> 6, l = tid & 63;
  const int wm = w >> 2, wn = w & 3;
  const int lr = l & 15, lg = l >> 4;

  int lin;
  {
    const int orig = blockIdx.y * gridDim.x + blockIdx.x;
    const int nwg = gridDim.x * gridDim.y;
    const int q = nwg >> 3, r = nwg & 7;
    const int x = orig & 7, idx = orig >> 3;
    lin = (x < r ? x * (q + 1) : r * (q + 1) + (x - r) * q) + idx;
  }
  const int bm = (lin % gridDim.x) * 256;
  const int bn = (lin / gridDim.x) * 256;

  auto stageA = [&](int tt, int h) {
    const int kb = tt * 64;
    const int lo = ((tt & 1) * 2 + h) * 8192;
#pragma unroll
    for (int c = 0; c < 2; ++c) {
      const int idx = c * 512 + tid;
      const int row = idx >> 3;
      const int col = ((idx & 7) ^ (row & 7)) * 8;
      gload_lds16(A + (size_t)(bm + h * 128 + row) * K + kb + col, SH + lo + idx * 8);
    }
  };
  auto stageB = [&](int tt, int h) {
    const int kb = tt * 64;
    const int lo = 32768 + ((tt & 1) * 2 + h) * 8192;
#pragma unroll
    for (int c = 0; c < 2; ++c) {
      const int idx = c * 512 + tid;
      const int row = idx >> 3;
      const int col = ((idx & 7) ^ (row & 7)) * 8;
      gload_lds16(BT + (size_t)(bn + h * 128 + row) * K + kb + col, SH + lo + idx * 8);
    }
  };

  f32x4 acc[8][4];
#pragma unroll
  for (int m = 0; m < 8; ++m)
#pragma unroll
    for (int n = 0; n < 4; ++n) acc[m][n] = (f32x4){0.f, 0.f, 0.f, 0.f};

  const int NT = K >> 6;
  stageA(0, 0); stageA(0, 1); stageB(0, 0); stageB(0, 1);
  stageA(1, 0); stageA(1, 1); stageB(1, 0); stageB(1, 1);
  asm volatile("s_waitcnt vmcnt(8)" ::: "memory");
  __builtin_amdgcn_s_barrier();
  __builtin_amdgcn_sched_barrier(0);

  const int aoffBase = wm * 8192;
  const int boffBase = 32768 + (wn >> 1) * 8192 + (wn & 1) * 64 * 64;
  const int sw = (lr & 7) << 3;

  for (int t = 0; t < NT; ++t) {
    const int b = t & 1;
    const int ao = b * 16384 + aoffBase;
    const int bo = boffBase + b * 16384;
    bf16x8 af[8], bfr[4];
#pragma unroll
    for (int m = 0; m < 8; ++m)
      af[m] = *(const bf16x8*)&SH[ao + (m * 16 + lr) * 64 + ((lg * 8) ^ sw)];
#pragma unroll
    for (int n = 0; n < 4; ++n)
      bfr[n] = *(const bf16x8*)&SH[bo + (n * 16 + lr) * 64 + ((lg * 8) ^ sw)];
    __builtin_amdgcn_s_setprio(1);
#pragma unroll
    for (int m = 0; m < 8; ++m)
#pragma unroll
      for (int n = 0; n < 4; ++n)
        acc[m][n] = __builtin_amdgcn_mfma_f32_16x16x32_bf16(af[m], bfr[n], acc[m][n], 0, 0, 0);
    __builtin_amdgcn_s_setprio(0);
#pragma unroll
    for (int m = 0; m < 8; ++m)
      af[m] = *(const bf16x8*)&SH[ao + (m * 16 + lr) * 64 + ((32 + lg * 8) ^ sw)];
#pragma unroll
    for (int n = 0; n < 4; ++n)
      bfr[n] = *(const bf16x8*)&SH[bo + (n * 16 + lr) * 64 + ((32 + lg * 8) ^ sw)];
    asm volatile("s_waitcnt lgkmcnt(0)" ::: "memory");
    __builtin_amdgcn_sched_barrier(0);
    __builtin_amdgcn_s_barrier();
    __builtin_amdgcn_sched_barrier(0);
    if (t + 2 < NT) {
      stageA(t + 2, 0); stageA(t + 2, 1); stageB(t + 2, 0); stageB(t + 2, 1);
    }
    __builtin_amdgcn_s_setprio(1);
#pragma unroll
    for (int m = 0; m < 8; ++m)
#pragma unroll
      for (int n = 0; n < 4; ++n)
        acc[m][n] = __builtin_amdgcn_mfma_f32_16x16x32_bf16(af[m], bfr[n], acc[m][n], 0, 0, 0);
    __builtin_amdgcn_s_setprio(0);
    if (t + 2 < NT) asm volatile("s_waitcnt vmcnt(8)" ::: "memory");
    else            asm volatile("s_waitcnt vmcnt(0)" ::: "memory");
    __builtin_amdgcn_s_barrier();
    __builtin_amdgcn_sched_barrier(0);
  }

#pragma unroll
  for (int m = 0; m < 8; ++m) {
    const int row0 = bm + wm * 128 + m * 16 + lg * 4;
#pragma unroll
    for (int n = 0; n < 4; ++n) {
      const int col = bn + wn * 64 + n * 16 + lr;
      const float bv = bias[col];
      if constexpr (EPI == 0) {
#pragma unroll
        for (int i = 0; i < 4; ++i)
          C[(size_t)(row0 + i) * N + col] = acc[m][n][i] + bv;
      } else {
        const int type = col >> 10;
        const int head = (col & 1023) >> 6;
        const int chn  = col & 63;
        unsigned short* dst = (type == 0) ? qbuf : ((type == 1) ? kbuf : vbuf);
        const float sc = (type == 0) ? 0.125f : 1.f;
#pragma unroll
        for (int i = 0; i < 4; ++i) {
          const int row = row0 + i;
          const int b_ = row / S_TOT;
          const int s_ = row - b_ * S_TOT;
          dst[(((size_t)(b_ * NHEAD + head)) * S_TOT + s_) * CH + chn] =
              f2h((acc[m][n][i] + bv) * sc);
        }
      }
    }
  }
}

// ---------------- MFMA img1: text + 7x7(k0) + 9x9 causal(k1), 3-phase flash ----------------
// 2-wave blocks; XCD-chunked work swizzle keeps 8 consecutive bh per XCD.
__global__ __launch_bounds__(128) __attribute__((amdgpu_waves_per_eu(2, 8)))
void attn_img1_mfma(
    const unsigned short* __restrict__ qb, const unsigned short* __restrict__ kb,
    const unsigned short* __restrict__ vtf, const unsigned short* __restrict__ maskT,
    short* __restrict__ ctx)
{
  __shared__ unsigned short ldsP[2][16][168];
  const int tid = threadIdx.x;
  const int w = tid >> 6, l = tid & 63;
  const int lr = l & 15, lg = l >> 4;
  const int work = (blockIdx.x & 7) * 1024 + (blockIdx.x >> 3);
  const int bh = work >> 7;
  const int qi = (work >> 1) & 63;
  const int qj0 = (work & 1) * 32 + w * 16;
  const int b_ = bh >> 4, head = bh & 15;
  const int s0 = OFF1 + qi * 64 + qj0;
  const size_t vrowbase = (size_t)bh * CH;
  unsigned short* myP = &ldsP[w][0][0];

  const unsigned short* qrow = qb + ((size_t)bh * S_TOT + s0 + lr) * CH + lg * 8;
  const f16x8 aq0 = ld8h(qrow);
  const f16x8 aq1 = ld8h(qrow + 32);

  float m[4], lsum[4];
  f32x4 acc[4];
#pragma unroll
  for (int i = 0; i < 4; ++i) { m[i] = -1e30f; lsum[i] = 0.f; }
#pragma unroll
  for (int n = 0; n < 4; ++n) acc[n] = (f32x4){0.f, 0.f, 0.f, 0.f};

  // ======== Phase C: text keys (masked) ========
  {
    f32x4 sC[4];
    const unsigned short* kb0 = kb + ((size_t)bh * S_TOT) * CH + lg * 8;
#pragma unroll
    for (int kt = 0; kt < 4; ++kt) {
      const unsigned short* krow = kb0 + (kt * 16 + lr) * CH;
      f32x4 a = (f32x4){0.f, 0.f, 0.f, 0.f};
      a = __builtin_amdgcn_mfma_f32_16x16x32_f16(aq0, ld8h(krow), a, 0, 0, 0);
      a = __builtin_amdgcn_mfma_f32_16x16x32_f16(aq1, ld8h(krow + 32), a, 0, 0, 0);
      sC[kt] = a;
    }
#pragma unroll
    for (int kt = 0; kt < 4; ++kt) {
      const unsigned short* mrow = maskT + (size_t)(kt * 16 + lr) * MTOT + (size_t)b_ * S_TOT + s0 + lg * 4;
#pragma unroll
      for (int i = 0; i < 4; ++i) {
        const float mv = __uint_as_float(((unsigned int)mrow[i]) << 16);
        sC[kt][i] = sC[kt][i] * mv - 10000.f * (1.f - mv);
      }
    }
    float rsc[4], la[4];
#pragma unroll
    for (int i = 0; i < 4; ++i) {
      float mx = fmaxf(fmaxf(sC[0][i], sC[1][i]), fmaxf(sC[2][i], sC[3][i]));
      mx = fmaxf(mx, __shfl_xor(mx, 1));
      mx = fmaxf(mx, __shfl_xor(mx, 2));
      mx = fmaxf(mx, __shfl_xor(mx, 4));
      mx = fmaxf(mx, __shfl_xor(mx, 8));
      const float mn = fmaxf(m[i], mx);
      rsc[i] = __expf(m[i] - mn);
      m[i] = mn;
      la[i] = 0.f;
    }
#pragma unroll
    for (int kt = 0; kt < 4; ++kt)
#pragma unroll
      for (int i = 0; i < 4; ++i) {
        const float p = __expf(sC[kt][i] - m[i]);
        la[i] += p;
        myP[(lg * 4 + i) * 168 + kt * 16 + lr] = f2h(p);
      }
#pragma unroll
    for (int i = 0; i < 4; ++i) {
      float li = la[i];
      li += __shfl_xor(li, 1);
      li += __shfl_xor(li, 2);
      li += __shfl_xor(li, 4);
      li += __shfl_xor(li, 8);
      lsum[i] = lsum[i] * rsc[i] + li;
#pragma unroll
      for (int n = 0; n < 4; ++n) acc[n][i] *= rsc[i];
    }
#pragma unroll
    for (int kt = 0; kt < 2; ++kt) {
      const f16x8 ap = __builtin_bit_cast(f16x8, *(const uint4*)&myP[lr * 168 + kt * 32 + lg * 8]);
      const int sbase = kt * 32 + lg * 8;
#pragma unroll
      for (int n = 0; n < 4; ++n) {
        const f16x8 bv = ld8h(vtf + (vrowbase + n * 16 + lr) * S_PAD + sbase);
        acc[n] = __builtin_amdgcn_mfma_f32_16x16x32_f16(ap, bv, acc[n], 0, 0, 0);
      }
    }
  }

  // ======== Phase A: 7x7 full window over k0 (32x32) ========
  {
    const int ki0 = qi >> 1, cb = (qj0 >> 1) - 3;
    f32x4 sA[7];
#pragma unroll
    for (int rr = 0; rr < 7; ++rr) sA[rr] = (f32x4){-1e30f, -1e30f, -1e30f, -1e30f};
    const unsigned short* kbA = kb + ((size_t)bh * S_TOT + OFF0) * CH + lg * 8;
    const int kjc = min(max(cb + lr, 0), 31);
#pragma unroll
    for (int rr = 0; rr < 7; ++rr) {
      const int ki = ki0 + rr - 3;
      if ((unsigned)ki < 32u) {
        const unsigned short* krow = kbA + (ki * 32 + kjc) * CH;
        f32x4 a = (f32x4){0.f, 0.f, 0.f, 0.f};
        a = __builtin_amdgcn_mfma_f32_16x16x32_f16(aq0, ld8h(krow), a, 0, 0, 0);
        a = __builtin_amdgcn_mfma_f32_16x16x32_f16(aq1, ld8h(krow + 32), a, 0, 0, 0);
        sA[rr] = a;
      }
    }
    const int kjA = cb + lr;
    float pmax[4] = {-1e30f, -1e30f, -1e30f, -1e30f};
#pragma unroll
    for (int rr = 0; rr < 7; ++rr) {
      const int ki = ki0 + rr - 3;
      const bool rv = (unsigned)ki < 32u;
#pragma unroll
      for (int i = 0; i < 4; ++i) {
        const int kjq = (qj0 + lg * 4 + i) >> 1;
        const int dj = kjA - kjq;
        const bool ok = rv && dj >= -3 && dj <= 3 && kjA >= 0 && kjA < 32;
        sA[rr][i] = ok ? sA[rr][i] : -1e30f;
        pmax[i] = fmaxf(pmax[i], sA[rr][i]);
      }
    }
    float rsc[4], la[4];
#pragma unroll
    for (int i = 0; i < 4; ++i) {
      float mx = pmax[i];
      mx = fmaxf(mx, __shfl_xor(mx, 1));
      mx = fmaxf(mx, __shfl_xor(mx, 2));
      mx = fmaxf(mx, __shfl_xor(mx, 4));
      mx = fmaxf(mx, __shfl_xor(mx, 8));
      const float mn = fmaxf(m[i], mx);
      rsc[i] = __expf(m[i] - mn);
      m[i] = mn;
      la[i] = 0.f;
    }
#pragma unroll
    for (int rr = 0; rr < 7; ++rr)
#pragma unroll
      for (int i = 0; i < 4; ++i) {
        const float p = __expf(sA[rr][i] - m[i]);
        la[i] += p;
        myP[(lg * 4 + i) * 168 + rr * 16 + lr] = f2h(p);
      }
#pragma unroll
    for (int j2 = 0; j2 < 4; ++j2)
      myP[lr * 168 + 112 + lg * 4 + j2] = 0;
#pragma unroll
    for (int i = 0; i < 4; ++i) {
      float li = la[i];
      li += __shfl_xor(li, 1);
      li += __shfl_xor(li, 2);
      li += __shfl_xor(li, 4);
      li += __shfl_xor(li, 8);
      lsum[i] = lsum[i] * rsc[i] + li;
#pragma unroll
      for (int n = 0; n < 4; ++n) acc[n][i] *= rsc[i];
    }
#pragma unroll
    for (int kt = 0; kt < 4; ++kt) {
      const f16x8 ap = __builtin_bit_cast(f16x8, *(const uint4*)&myP[lr * 168 + kt * 32 + lg * 8]);
      const int rowidx = 2 * kt + (lg >> 1);
      const int kiv = min(max(ki0 + rowidx - 3, 0), 31);
      const int sbase = OFF0 + kiv * 32 + cb + (lg & 1) * 8;
#pragma unroll
      for (int n = 0; n < 4; ++n) {
        const f16x8 bv = ld8h(vtf + (vrowbase + n * 16 + lr) * S_PAD + sbase);
        acc[n] = __builtin_amdgcn_mfma_f32_16x16x32_f16(ap, bv, acc[n], 0, 0, 0);
      }
    }
  }

  // ======== Phase B: 9x9 causal window over k1 (64x64) ========
  {
    const int cbB = qj0 - 4;
    f32x4 sB[10];
#pragma unroll
    for (int rr = 0; rr < 10; ++rr) sB[rr] = (f32x4){-1e30f, -1e30f, -1e30f, -1e30f};
    const unsigned short* kbB = kb + ((size_t)bh * S_TOT + OFF1) * CH + lg * 8;
#pragma unroll
    for (int rr = 0; rr < 5; ++rr) {
      const int ki = qi + rr - 4;
      if (ki >= 0) {
#pragma unroll
        for (int t = 0; t < 2; ++t) {
          const int kjc = min(max(cbB + t * 16 + lr, 0), 63);
          const unsigned short* krow = kbB + (ki * 64 + kjc) * CH;
          f32x4 a = (f32x4){0.f, 0.f, 0.f, 0.f};
          a = __builtin_amdgcn_mfma_f32_16x16x32_f16(aq0, ld8h(krow), a, 0, 0, 0);
          a = __builtin_amdgcn_mfma_f32_16x16x32_f16(aq1, ld8h(krow + 32), a, 0, 0, 0);
          sB[rr * 2 + t] = a;
        }
      }
    }
    float pmax[4] = {-1e30f, -1e30f, -1e30f, -1e30f};
#pragma unroll
    for (int rr = 0; rr < 5; ++rr) {
      const int djmax = (rr == 4) ? 0 : 4;
#pragma unroll
      for (int t = 0; t < 2; ++t) {
        const int kj = cbB + t * 16 + lr;
#pragma unroll
        for (int i = 0; i < 4; ++i) {
          const int qj = qj0 + lg * 4 + i;
          const int dj = kj - qj;
          const bool ok = dj >= -4 && dj <= djmax && kj >= 0 && kj < 64;
          sB[rr * 2 + t][i] = ok ? sB[rr * 2 + t][i] : -1e30f;
          pmax[i] = fmaxf(pmax[i], sB[rr * 2 + t][i]);
        }
      }
    }
    float rsc[4], la[4];
#pragma unroll
    for (int i = 0; i < 4; ++i) {
      float mx = pmax[i];
      mx = fmaxf(mx, __shfl_xor(mx, 1));
      mx = fmaxf(mx, __shfl_xor(mx, 2));
      mx = fmaxf(mx, __shfl_xor(mx, 4));
      mx = fmaxf(mx, __shfl_xor(mx, 8));
      const float mn = fmaxf(m[i], mx);
      rsc[i] = __expf(m[i] - mn);
      m[i] = mn;
      la[i] = 0.f;
    }
#pragma unroll
    for (int rr = 0; rr < 5; ++rr)
#pragma unroll
      for (int t = 0; t < 2; ++t)
#pragma unroll
        for (int i = 0; i < 4; ++i) {
          const float p = __expf(sB[rr * 2 + t][i] - m[i]);
          la[i] += p;
          myP[(lg * 4 + i) * 168 + rr * 32 + t * 16 + lr] = f2h(p);
        }
#pragma unroll
    for (int i = 0; i < 4; ++i) {
      float li = la[i];
      li += __shfl_xor(li, 1);
      li += __shfl_xor(li, 2);
      li += __shfl_xor(li, 4);
      li += __shfl_xor(li, 8);
      lsum[i] = lsum[i] * rsc[i] + li;
#pragma unroll
      for (int n = 0; n < 4; ++n) acc[n][i] *= rsc[i];
    }
#pragma unroll
    for (int kt = 0; kt < 5; ++kt) {
      const f16x8 ap = __builtin_bit_cast(f16x8, *(const uint4*)&myP[lr * 168 + kt * 32 + lg * 8]);
      const int kiv = max(qi + kt - 4, 0);
      const int sbase = OFF1 + kiv * 64 + cbB + lg * 8;
#pragma unroll
      for (int n = 0; n < 4; ++n) {
        const f16x8 bv = ld8h(vtf + (vrowbase + n * 16 + lr) * S_PAD + sbase);
        acc[n] = __builtin_amdgcn_mfma_f32_16x16x32_f16(ap, bv, acc[n], 0, 0, 0);
      }
    }
  }

  // ======== finalize ========
  const int ki0f = qi >> 1;
#pragma unroll
  for (int i = 0; i < 4; ++i) {
    const int qj = qj0 + lg * 4 + i;
    const int kjq = qj >> 1;
    const int nInvA = max(0, 3 - ki0f) + max(0, ki0f - 28);
    const int oobA  = max(0, 3 - kjq) + max(0, kjq - 28);
    const int nInvB = max(0, 4 - qi);
    const int oobB  = max(0, 4 - qj) + max(0, qj - 59);
    const int cnt = nInvA * 7 + (7 - nInvA) * oobA
                  + nInvB * 9 + (4 - nInvB) * oobB + max(0, 4 - qj);
    const float lf = lsum[i] + (float)cnt * __expf(-m[i]);
    const float inv = 1.f / lf;
    short* cp = ctx + ((size_t)(b_ * S_TOT) + s0 + lg * 4 + i) * HID + head * CH;
#pragma unroll
    for (int n = 0; n < 4; ++n)
      cp[n * 16 + lr] = (short)f2bf(acc[n][i] * inv);
  }
}

// ---------------- MFMA img0: text + 9x9 causal(k0), single-softmax flash ----------------
__global__ __launch_bounds__(128) __attribute__((amdgpu_waves_per_eu(2, 8)))
void attn_img0_mfma(
    const unsigned short* __restrict__ qb, const unsigned short* __restrict__ kb,
    const unsigned short* __restrict__ vtf, const unsigned short* __restrict__ maskT,
    short* __restrict__ ctx)
{
  __shared__ unsigned short ldsP[2][16][168];
  const int tid = threadIdx.x;
  const int w = tid >> 6, l = tid & 63;
  const int lr = l & 15, lg = l >> 4;
  const int swz = (blockIdx.x & 7) * ((BN_TOT * 32) >> 3) + (blockIdx.x >> 3);
  const int bh = swz >> 5;
  const int qi = swz & 31;
  const int qj0 = w * 16;
  const int b_ = bh >> 4, head = bh & 15;
  const int s0 = OFF0 + qi * 32 + qj0;
  const size_t vrowbase = (size_t)bh * CH;
  unsigned short* myP = &ldsP[w][0][0];

  const unsigned short* qrow = qb + ((size_t)bh * S_TOT + s0 + lr) * CH + lg * 8;
  const f16x8 aq0 = ld8h(qrow);
  const f16x8 aq1 = ld8h(qrow + 32);

  f32x4 sC[4];
  {
    const unsigned short* kb0 = kb + ((size_t)bh * S_TOT) * CH + lg * 8;
#pragma unroll
    for (int kt = 0; kt < 4; ++kt) {
      const unsigned short* krow = kb0 + (kt * 16 + lr) * CH;
      f32x4 a = (f32x4){0.f, 0.f, 0.f, 0.f};
      a = __builtin_amdgcn_mfma_f32_16x16x32_f16(aq0, ld8h(krow), a, 0, 0, 0);
      a = __builtin_amdgcn_mfma_f32_16x16x32_f16(aq1, ld8h(krow + 32), a, 0, 0, 0);
      sC[kt] = a;
    }
  }
  const int cbB = qj0 - 4;
  f32x4 sB[10];
  {
#pragma unroll
    for (int rr = 0; rr < 10; ++rr) sB[rr] = (f32x4){-1e30f, -1e30f, -1e30f, -1e30f};
    const unsigned short* kbB = kb + ((size_t)bh * S_TOT + OFF0) * CH + lg * 8;
#pragma unroll
    for (int rr = 0; rr < 5; ++rr) {
      const int ki = qi + rr - 4;
      if (ki >= 0) {
#pragma unroll
        for (int t = 0; t < 2; ++t) {
          const int kjc = min(max(cbB + t * 16 + lr, 0), 31);
          const unsigned short* krow = kbB + (ki * 32 + kjc) * CH;
          f32x4 a = (f32x4){0.f, 0.f, 0.f, 0.f};
          a = __builtin_amdgcn_mfma_f32_16x16x32_f16(aq0, ld8h(krow), a, 0, 0, 0);
          a = __builtin_amdgcn_mfma_f32_16x16x32_f16(aq1, ld8h(krow + 32), a, 0, 0, 0);
          sB[rr * 2 + t] = a;
        }
      }
    }
  }

#pragma unroll
  for (int kt = 0; kt < 4; ++kt) {
    const unsigned short* mrow = maskT + (size_t)(kt * 16 + lr) * MTOT + (size_t)b_ * S_TOT + s0 + lg * 4;
#pragma unroll
    for (int i = 0; i < 4; ++i) {
      const float mv = __uint_as_float(((unsigned int)mrow[i]) << 16);
      sC[kt][i] = sC[kt][i] * mv - 10000.f * (1.f - mv);
    }
  }
#pragma unroll
  for (int rr = 0; rr < 5; ++rr) {
    const int djmax = (rr == 4) ? 0 : 4;
#pragma unroll
    for (int t = 0; t < 2; ++t) {
      const int kj = cbB + t * 16 + lr;
#pragma unroll
      for (int i = 0; i < 4; ++i) {
        const int qj = qj0 + lg * 4 + i;
        const int dj = kj - qj;
        const bool ok = dj >= -4 && dj <= djmax && kj >= 0 && kj < 32;
        sB[rr * 2 + t][i] = ok ? sB[rr * 2 + t][i] : -1e30f;
      }
    }
  }

  float m[4], lsum[4];
#pragma unroll
  for (int i = 0; i < 4; ++i) {
    float mx = fmaxf(fmaxf(sC[0][i], sC[1][i]), fmaxf(sC[2][i], sC[3][i]));
#pragma unroll
    for (int rr = 0; rr < 10; ++rr) mx = fmaxf(mx, sB[rr][i]);
    mx = fmaxf(mx, __shfl_xor(mx, 1));
    mx = fmaxf(mx, __shfl_xor(mx, 2));
    mx = fmaxf(mx, __shfl_xor(mx, 4));
    mx = fmaxf(mx, __shfl_xor(mx, 8));
    m[i] = mx;
    float li = 0.f;
#pragma unroll
    for (int kt = 0; kt < 4; ++kt) { const float p = __expf(sC[kt][i] - mx); sC[kt][i] = p; li += p; }
#pragma unroll
    for (int rr = 0; rr < 10; ++rr) { const float p = __expf(sB[rr][i] - mx); sB[rr][i] = p; li += p; }
    li += __shfl_xor(li, 1);
    li += __shfl_xor(li, 2);
    li += __shfl_xor(li, 4);
    li += __shfl_xor(li, 8);
    lsum[i] = li;
  }

  f32x4 acc[4];
#pragma unroll
  for (int n = 0; n < 4; ++n) acc[n] = (f32x4){0.f, 0.f, 0.f, 0.f};

  {
#pragma unroll
    for (int kt = 0; kt < 4; ++kt)
#pragma unroll
      for (int i = 0; i < 4; ++i)
        myP[(lg * 4 + i) * 168 + kt * 16 + lr] = f2h(sC[kt][i]);
#pragma unroll
    for (int kt = 0; kt < 2; ++kt) {
      const f16x8 ap = __builtin_bit_cast(f16x8, *(const uint4*)&myP[lr * 168 + kt * 32 + lg * 8]);
      const int sbase = kt * 32 + lg * 8;
#pragma unroll
      for (int n = 0; n < 4; ++n) {
        const f16x8 bv = ld8h(vtf + (vrowbase + n * 16 + lr) * S_PAD + sbase);
        acc[n] = __builtin_amdgcn_mfma_f32_16x16x32_f16(ap, bv, acc[n], 0, 0, 0);
      }
    }
  }
  {
#pragma unroll
    for (int rr = 0; rr < 5; ++rr)
#pragma unroll
      for (int t = 0; t < 2; ++t)
#pragma unroll
        for (int i = 0; i < 4; ++i)
          myP[(lg * 4 + i) * 168 + rr * 32 + t * 16 + lr] = f2h(sB[rr * 2 + t][i]);
#pragma unroll
    for (int kt = 0; kt < 5; ++kt) {
      const f16x8 ap = __builtin_bit_cast(f16x8, *(const uint4*)&myP[lr * 168 + kt * 32 + lg * 8]);
      const int kiv = max(qi + kt - 4, 0);
      const int sbase = OFF0 + kiv * 32 + cbB + lg * 8;
#pragma unroll
      for (int n = 0; n < 4; ++n) {
        const f16x8 bv = ld8h(vtf + (vrowbase + n * 16 + lr) * S_PAD + sbase);
        acc[n] = __builtin_amdgcn_mfma_f32_16x16x32_f16(ap, bv, acc[n], 0, 0, 0);
      }
    }
  }

#pragma unroll
  for (int i = 0; i < 4; ++i) {
    const int qj = qj0 + lg * 4 + i;
    const int nInvB = max(0, 4 - qi);
    const int oobB  = max(0, 4 - qj) + max(0, qj - 27);
    const int cnt = nInvB * 9 + (4 - nInvB) * oobB + max(0, 4 - qj);
    const float lf = lsum[i] + (float)cnt * __expf(-m[i]);
    const float inv = 1.f / lf;
    short* cp = ctx + ((size_t)(b_ * S_TOT) + s0 + lg * 4 + i) * HID + head * CH;
#pragma unroll
    for (int n = 0; n < 4; ++n)
      cp[n * 16 + lr] = (short)f2bf(acc[n][i] * inv);
  }
}

// ---------------- scalar attention core (f16, dot2, 8 lanes/query) ----------------
__device__ __forceinline__ float dot8h(const uint4 qd, const unsigned short* __restrict__ kp) {
  const uint4 a = *(const uint4*)kp;
  float s = 0.f;
  s = fd2(a.x, qd.x, s); s = fd2(a.y, qd.y, s);
  s = fd2(a.z, qd.z, s); s = fd2(a.w, qd.w, s);
  return s;
}
__device__ __forceinline__ void pv2d(float& a0, float& a1, unsigned int dA, unsigned int dB, h2v pp) {
  a0 = __builtin_amdgcn_fdot2(h2(pklo(dA, dB)), pp, a0, false);
  a1 = __builtin_amdgcn_fdot2(h2(pkhi(dA, dB)), pp, a1, false);
}
__device__ __forceinline__ void pv2q(float* __restrict__ acc, uint4 A, uint4 B, h2v pp) {
  pv2d(acc[0], acc[1], A.x, B.x, pp);
  pv2d(acc[2], acc[3], A.y, B.y, pp);
  pv2d(acc[4], acc[5], A.z, B.z, pp);
  pv2d(acc[6], acc[7], A.w, B.w, pp);
}

template<int W, bool MASKED>
__device__ __forceinline__ void row_upd(const uint4 qd,
                                        const unsigned short* __restrict__ krow,
                                        const unsigned short* __restrict__ vrow,
                                        const int kj0, const int limit,
                                        const unsigned short* __restrict__ maskT,
                                        const int rowIdx,
                                        float& m, float& l, float* __restrict__ acc, int& cnt) {
  float s[W];
#pragma unroll
  for (int j = 0; j < W; ++j) {
    const int kj = kj0 + j;
    const bool ok = (unsigned)kj < (unsigned)limit;
    float d = dot8h(qd, krow + (ok ? kj : 0) * CH);
    d += __shfl_xor(d, 1);
    d += __shfl_xor(d, 2);
    d += __shfl_xor(d, 4);
    if constexpr (MASKED) {
      const float mv = __uint_as_float(((unsigned int)maskT[(size_t)kj * MTOT + rowIdx]) << 16);
      s[j] = d * mv - 10000.f * (1.f - mv);
    } else {
      s[j] = ok ? d : -1e30f;
      cnt += ok ? 0 : 1;
    }
  }
  float smax = s[0];
#pragma unroll
  for (int j = 1; j < W; ++j) smax = fmaxf(smax, s[j]);
  const float mn = fmaxf(m, smax);
  const float r = __expf(m - mn);
  m = mn;
  l *= r;
#pragma unroll
  for (int i = 0; i < 8; ++i) acc[i] *= r;
  float p[W];
#pragma unroll
  for (int j = 0; j < W; ++j) { p[j] = __expf(s[j] - mn); l += p[j]; }
#pragma unroll
  for (int j = 0; j < W; j += 2) {
    const int kja = kj0 + j;
    const bool oka = (unsigned)kja < (unsigned)limit;
    const uint4 A = *(const uint4*)(vrow + (oka ? kja : 0) * CH);
    uint4 B; float pb;
    if (j + 1 < W) {
      const int kjb = kja + 1;
      const bool okb = (unsigned)kjb < (unsigned)limit;
      B = *(const uint4*)(vrow + (okb ? kjb : 0) * CH);
      pb = p[j + 1];
    } else {
      B = A; pb = 0.f;
    }
    const h2v pp = __builtin_bit_cast(h2v, __builtin_amdgcn_cvt_pkrtz(p[j], pb));
    pv2q(acc, A, B, pp);
  }
}

__device__ __forceinline__ void store_q8(short* ctx, size_t base,
                                         const float* acc, float inv) {
  unsigned int* cp = (unsigned int*)(ctx + base);
#pragma unroll
  for (int i = 0; i < 4; ++i)
    cp[i] = f2bf(acc[2 * i] * inv) | (f2bf(acc[2 * i + 1] * inv) << 16);
}

// ---------------- attention: text queries (scalar) ----------------
__global__ __launch_bounds__(256) __attribute__((amdgpu_waves_per_eu(4, 8)))
void attn_text(
    const unsigned short* __restrict__ qb, const unsigned short* __restrict__ kb,
    const unsigned short* __restrict__ vb, const unsigned short* __restrict__ maskT,
    short* __restrict__ ctx)
{
  const int t = blockIdx.x * 256 + threadIdx.x;
  const int oct = t & 7;
  const int qidx = t >> 3;
  const int bh = qidx >> 6;
  const int tq = qidx & 63;
  const int b_ = bh >> 4, head = bh & 15;

  const uint4 qd = *(const uint4*)(qb + ((size_t)bh * S_TOT + tq) * CH + oct * 8);

  float m = -1e30f, l = 0.f;
  float acc[8];
#pragma unroll
  for (int i = 0; i < 8; ++i) acc[i] = 0.f;
  int cnt = 0;

  const unsigned short* kt = kb + (size_t)bh * S_TOT * CH + oct * 8;
  const unsigned short* vt = vb + (size_t)bh * S_TOT * CH + oct * 8;
  const int rowIdx = b_ * S_TOT + tq;
  for (int t8 = 0; t8 < 8; ++t8)
    row_upd<8, true>(qd, kt, vt, t8 * 8, T_TXT, maskT, rowIdx, m, l, acc, cnt);
  store_q8(ctx, ((size_t)rowIdx) * HID + head * CH + oct * 8, acc, 1.f / l);
}

// ---------------- launch ----------------
extern "C" void kernel_launch(void* const* d_in, const int* in_sizes, int n_in,
                              void* d_out, int out_size, void* d_ws, size_t ws_size,
                              hipStream_t stream) {
  const float* hidden = (const float*)d_in[0];
  const float* mask   = (const float*)d_in[1];
  const float* w_qkv  = (const float*)d_in[2];
  const float* b_qkv  = (const float*)d_in[3];
  const float* w_out  = (const float*)d_in[4];
  const float* b_out  = (const float*)d_in[5];
  float* out = (float*)d_out;

  const size_t NB = (size_t)BN_TOT * S_TOT * CH;
  unsigned short* qbuf = (unsigned short*)d_ws;    // f16
  unsigned short* kbuf = qbuf + NB;
  unsigned short* vbuf = kbuf + NB;
  short* hbf   = (short*)(vbuf + NB);              // hidden bf16; later ALIASED as ctx bf16
  short* wqkvT = hbf + NB;
  short* woutT = wqkvT + (size_t)3072 * 1024;
  short* maskT = woutT + (size_t)1024 * 1024;
  unsigned short* vtf = (unsigned short*)(maskT + (size_t)T_TXT * MTOT);  // V^T [64*64][S_PAD]

  // 0) conversions
  cvt_bf16<<<(int)((NB / 8 + 255) / 256), 256, 0, stream>>>(hidden, (unsigned int*)hbf, (int)(NB / 8));
  cvt_T<<<dim3(3072 / 32, 1024 / 32), dim3(32, 8), 0, stream>>>(w_qkv, wqkvT, 1024, 3072);
  cvt_T<<<dim3(1024 / 32, 1024 / 32), dim3(32, 8), 0, stream>>>(w_out, woutT, 1024, 1024);
  cvt_T<<<dim3(T_TXT / 32, MTOT / 32), dim3(32, 8), 0, stream>>>(mask, maskT, MTOT, T_TXT);

  // 1) QKV projection (256x256 deep-pipelined) with f16 q/k/v scatter epilogue
  gemm_mfma256<1><<<dim3(MTOT / 256, 3072 / 256), 512, 0, stream>>>(
      hbf, wqkvT, b_qkv, nullptr, qbuf, kbuf, vbuf, MTOT, 3072, 1024);

  // 1b) coalesced V transpose: vbuf -> vtf
  cvt_Tv<<<dim3(CH / 32, S_TOT / 32, BN_TOT), dim3(32, 8), 0, stream>>>(vbuf, vtf);

  // 2) attention (all-MFMA for image queries; XCD-chunked swizzle)
  short* ctx = hbf;
  attn_text<<<(BN_TOT * T_TXT * 8) / 256, 256, 0, stream>>>(qbuf, kbuf, vbuf, (unsigned short*)maskT, ctx);
  attn_img0_mfma<<<BN_TOT * 32, 128, 0, stream>>>(qbuf, kbuf, vtf, (unsigned short*)maskT, ctx);
  attn_img1_mfma<<<BN_TOT * 64 * 2, 128, 0, stream>>>(qbuf, kbuf, vtf, (unsigned short*)maskT, ctx);

  // 3) output projection (256x256 deep-pipelined)
  gemm_mfma256<0><<<dim3(MTOT / 256, 1024 / 256), 512, 0, stream>>>(
      ctx, woutT, b_out, out, nullptr, nullptr, nullptr, MTOT, 1024, 1024);
}